// Round 1
// baseline (206.169 us; speedup 1.0000x reference)
//
#include <hip/hip_runtime.h>
#include <math.h>

#define BATCH 16384
#define MAXF 32
#define NFEAT 768
#define FT_OUT 1024

__global__ __launch_bounds__(256, 4) void nnboard_kernel(
    const float* __restrict__ values,
    const int*   __restrict__ stm_idx,
    const int*   __restrict__ nstm_idx,
    const float* __restrict__ ft_w,
    const float* __restrict__ ft_b,
    const float* __restrict__ out_w,
    const float* __restrict__ out_b,
    float*       __restrict__ out)
{
    const int b = blockIdx.x;
    const int t = threadIdx.x;

    __shared__ int   s_stm[MAXF];
    __shared__ int   s_nstm[MAXF];
    __shared__ float s_val[MAXF];
    __shared__ float s_red[4];

    if (t < MAXF) {
        s_stm[t]  = stm_idx[b * MAXF + t];
        s_nstm[t] = nstm_idx[b * MAXF + t];
        s_val[t]  = values[b * MAXF + t];
    }
    __syncthreads();

    // thread t owns output columns d = 4t .. 4t+3   (256 threads * 4 = 1024)
    const int d4 = t * 4;

    float4 acc_s = make_float4(0.f, 0.f, 0.f, 0.f);
    float4 acc_n = make_float4(0.f, 0.f, 0.f, 0.f);

    #pragma unroll 8
    for (int f = 0; f < MAXF; ++f) {
        const float v = s_val[f];
        const float4 rs = *(const float4*)(ft_w + (size_t)s_stm[f]  * FT_OUT + d4);
        const float4 rn = *(const float4*)(ft_w + (size_t)s_nstm[f] * FT_OUT + d4);
        acc_s.x = fmaf(v, rs.x, acc_s.x);
        acc_s.y = fmaf(v, rs.y, acc_s.y);
        acc_s.z = fmaf(v, rs.z, acc_s.z);
        acc_s.w = fmaf(v, rs.w, acc_s.w);
        acc_n.x = fmaf(v, rn.x, acc_n.x);
        acc_n.y = fmaf(v, rn.y, acc_n.y);
        acc_n.z = fmaf(v, rn.z, acc_n.z);
        acc_n.w = fmaf(v, rn.w, acc_n.w);
    }

    // bias + clip + dot with out_w (stm half at [d], nstm half at [FT_OUT + d])
    const float4 bias = *(const float4*)(ft_b + d4);
    const float4 ws   = *(const float4*)(out_w + d4);
    const float4 wn   = *(const float4*)(out_w + FT_OUT + d4);

    auto crelu = [](float x) { return fminf(fmaxf(x, 0.f), 1.f); };

    float partial = 0.f;
    partial += crelu(acc_s.x + bias.x) * ws.x;
    partial += crelu(acc_s.y + bias.y) * ws.y;
    partial += crelu(acc_s.z + bias.z) * ws.z;
    partial += crelu(acc_s.w + bias.w) * ws.w;
    partial += crelu(acc_n.x + bias.x) * wn.x;
    partial += crelu(acc_n.y + bias.y) * wn.y;
    partial += crelu(acc_n.z + bias.z) * wn.z;
    partial += crelu(acc_n.w + bias.w) * wn.w;

    // wave (64-lane) shuffle reduce
    #pragma unroll
    for (int off = 32; off > 0; off >>= 1)
        partial += __shfl_down(partial, off, 64);

    const int wave = t >> 6;
    if ((t & 63) == 0) s_red[wave] = partial;
    __syncthreads();

    if (t == 0) {
        const float total = s_red[0] + s_red[1] + s_red[2] + s_red[3] + out_b[0];
        out[b] = 1.f / (1.f + expf(-total));
    }
}

extern "C" void kernel_launch(void* const* d_in, const int* in_sizes, int n_in,
                              void* d_out, int out_size, void* d_ws, size_t ws_size,
                              hipStream_t stream) {
    const float* values   = (const float*)d_in[0];
    const int*   stm_idx  = (const int*)d_in[1];
    const int*   nstm_idx = (const int*)d_in[2];
    const float* ft_w     = (const float*)d_in[3];
    const float* ft_b     = (const float*)d_in[4];
    const float* out_w    = (const float*)d_in[5];
    const float* out_b    = (const float*)d_in[6];
    float*       out      = (float*)d_out;

    nnboard_kernel<<<BATCH, 256, 0, stream>>>(
        values, stm_idx, nstm_idx, ft_w, ft_b, out_w, out_b, out);
}

// Round 2
// 146.927 us; speedup vs baseline: 1.4032x; 1.4032x over previous
//
#include <hip/hip_runtime.h>
#include <hip/hip_bf16.h>
#include <math.h>

#define BATCH 16384
#define MAXF 32
#define NFEAT 768
#define FT_OUT 1024

typedef unsigned short ushort_t;
typedef unsigned int uint_t;

__device__ __forceinline__ float bf_lo(uint_t u) { return __uint_as_float(u << 16); }
__device__ __forceinline__ float bf_hi(uint_t u) { return __uint_as_float(u & 0xffff0000u); }

// Phase 0: convert fp32 table -> bf16 (RNE) in workspace. 768*1024 = 786432 elems.
__global__ __launch_bounds__(256) void convert_kernel(const float* __restrict__ ft_w,
                                                      ushort_t* __restrict__ tab) {
    const int i = (blockIdx.x * 256 + threadIdx.x) * 4;
    float4 f = *(const float4*)(ft_w + i);
    __hip_bfloat16 h0 = __float2bfloat16(f.x);
    __hip_bfloat16 h1 = __float2bfloat16(f.y);
    __hip_bfloat16 h2 = __float2bfloat16(f.z);
    __hip_bfloat16 h3 = __float2bfloat16(f.w);
    ushort4 u;
    u.x = *reinterpret_cast<ushort_t*>(&h0);
    u.y = *reinterpret_cast<ushort_t*>(&h1);
    u.z = *reinterpret_cast<ushort_t*>(&h2);
    u.w = *reinterpret_cast<ushort_t*>(&h3);
    *(ushort4*)(tab + i) = u;
}

// Phase 1: one 128-thread block per sample; thread t owns columns 8t..8t+7.
// Each lane reads 16 B (8 bf16 cols) per gathered row -> perfectly coalesced.
__global__ __launch_bounds__(128, 8) void nnboard_main(
    const float* __restrict__ values,
    const int*   __restrict__ stm_idx,
    const int*   __restrict__ nstm_idx,
    const ushort_t* __restrict__ tab,
    const float* __restrict__ ft_b,
    const float* __restrict__ out_w,
    const float* __restrict__ out_b,
    float*       __restrict__ out)
{
    const int b = blockIdx.x;
    const int t = threadIdx.x;

    __shared__ int   s_stm[MAXF];
    __shared__ int   s_nstm[MAXF];
    __shared__ float s_val[MAXF];
    __shared__ float s_red[2];

    if (t < MAXF) {
        s_stm[t]  = stm_idx[b * MAXF + t];
        s_nstm[t] = nstm_idx[b * MAXF + t];
        s_val[t]  = values[b * MAXF + t];
    }
    __syncthreads();

    const int d8 = t * 8;

    float accs[8] = {0.f, 0.f, 0.f, 0.f, 0.f, 0.f, 0.f, 0.f};
    float accn[8] = {0.f, 0.f, 0.f, 0.f, 0.f, 0.f, 0.f, 0.f};

    #pragma unroll 4
    for (int f = 0; f < MAXF; ++f) {
        const float v = s_val[f];
        const uint4 qs = *(const uint4*)(tab + (size_t)s_stm[f]  * FT_OUT + d8);
        const uint4 qn = *(const uint4*)(tab + (size_t)s_nstm[f] * FT_OUT + d8);
        accs[0] = fmaf(v, bf_lo(qs.x), accs[0]);
        accs[1] = fmaf(v, bf_hi(qs.x), accs[1]);
        accs[2] = fmaf(v, bf_lo(qs.y), accs[2]);
        accs[3] = fmaf(v, bf_hi(qs.y), accs[3]);
        accs[4] = fmaf(v, bf_lo(qs.z), accs[4]);
        accs[5] = fmaf(v, bf_hi(qs.z), accs[5]);
        accs[6] = fmaf(v, bf_lo(qs.w), accs[6]);
        accs[7] = fmaf(v, bf_hi(qs.w), accs[7]);
        accn[0] = fmaf(v, bf_lo(qn.x), accn[0]);
        accn[1] = fmaf(v, bf_hi(qn.x), accn[1]);
        accn[2] = fmaf(v, bf_lo(qn.y), accn[2]);
        accn[3] = fmaf(v, bf_hi(qn.y), accn[3]);
        accn[4] = fmaf(v, bf_lo(qn.z), accn[4]);
        accn[5] = fmaf(v, bf_hi(qn.z), accn[5]);
        accn[6] = fmaf(v, bf_lo(qn.w), accn[6]);
        accn[7] = fmaf(v, bf_hi(qn.w), accn[7]);
    }

    // bias + clip + dot with out_w; stm half at [d], nstm half at [FT_OUT + d]
    float partial = 0.f;
    #pragma unroll
    for (int j = 0; j < 8; ++j) {
        const float bj = ft_b[d8 + j];
        const float hs = fminf(fmaxf(accs[j] + bj, 0.f), 1.f);
        const float hn = fminf(fmaxf(accn[j] + bj, 0.f), 1.f);
        partial = fmaf(hs, out_w[d8 + j], partial);
        partial = fmaf(hn, out_w[FT_OUT + d8 + j], partial);
    }

    // wave (64-lane) shuffle reduce, then combine 2 waves
    #pragma unroll
    for (int off = 32; off > 0; off >>= 1)
        partial += __shfl_down(partial, off, 64);

    if ((t & 63) == 0) s_red[t >> 6] = partial;
    __syncthreads();

    if (t == 0) {
        const float total = s_red[0] + s_red[1] + out_b[0];
        out[b] = 1.f / (1.f + expf(-total));
    }
}

extern "C" void kernel_launch(void* const* d_in, const int* in_sizes, int n_in,
                              void* d_out, int out_size, void* d_ws, size_t ws_size,
                              hipStream_t stream) {
    const float* values   = (const float*)d_in[0];
    const int*   stm_idx  = (const int*)d_in[1];
    const int*   nstm_idx = (const int*)d_in[2];
    const float* ft_w     = (const float*)d_in[3];
    const float* ft_b     = (const float*)d_in[4];
    const float* out_w    = (const float*)d_in[5];
    const float* out_b    = (const float*)d_in[6];
    float*       out      = (float*)d_out;

    ushort_t* tab = (ushort_t*)d_ws;  // 768*1024*2 = 1.5 MB bf16 table

    convert_kernel<<<(NFEAT * FT_OUT) / (256 * 4), 256, 0, stream>>>(ft_w, tab);
    nnboard_main<<<BATCH, 128, 0, stream>>>(
        values, stm_idx, nstm_idx, tab, ft_b, out_w, out_b, out);
}

// Round 3
// 144.961 us; speedup vs baseline: 1.4222x; 1.0136x over previous
//
#include <hip/hip_runtime.h>
#include <hip/hip_fp16.h>
#include <math.h>

#define BATCH 16384
#define MAXF 32
#define NFEAT 768
#define FT_OUT 1024

typedef unsigned int uint_t;

// Phase 0: convert fp32 table -> f16 in workspace. 768*1024 elems, 4/thread.
__global__ __launch_bounds__(256) void convert_kernel(const float* __restrict__ ft_w,
                                                      __half2* __restrict__ tab) {
    const int i = (blockIdx.x * 256 + threadIdx.x) * 4;   // element index
    float4 f = *(const float4*)(ft_w + i);
    __half2 lo = __floats2half2_rn(f.x, f.y);
    __half2 hi = __floats2half2_rn(f.z, f.w);
    tab[(i >> 1) + 0] = lo;
    tab[(i >> 1) + 1] = hi;
}

// Phase 1: one 128-thread block per sample; thread t owns columns 8t..8t+7.
// Each lane reads 16 B (8 f16 cols) per gathered row -> coalesced dwordx4.
// Accumulate in packed f16 via v_pk_fma_f16 (__hfma2): 2 cols per instr, no unpack.
__global__ __launch_bounds__(128, 8) void nnboard_main(
    const float* __restrict__ values,
    const int*   __restrict__ stm_idx,
    const int*   __restrict__ nstm_idx,
    const __half* __restrict__ tab,
    const float* __restrict__ ft_b,
    const float* __restrict__ out_w,
    const float* __restrict__ out_b,
    float*       __restrict__ out)
{
    const int b = blockIdx.x;
    const int t = threadIdx.x;

    __shared__ int   s_stm[MAXF];
    __shared__ int   s_nstm[MAXF];
    __shared__ float s_val[MAXF];
    __shared__ float s_red[2];

    if (t < MAXF) {
        s_stm[t]  = stm_idx[b * MAXF + t];
        s_nstm[t] = nstm_idx[b * MAXF + t];
        s_val[t]  = values[b * MAXF + t];
    }
    __syncthreads();

    const int d8 = t * 8;

    __half2 zero2 = __float2half2_rn(0.f);
    __half2 accs[4] = {zero2, zero2, zero2, zero2};
    __half2 accn[4] = {zero2, zero2, zero2, zero2};

    #pragma unroll 4
    for (int f = 0; f < MAXF; ++f) {
        const __half2 v2 = __float2half2_rn(s_val[f]);
        const uint4 qs = *(const uint4*)(tab + (size_t)s_stm[f]  * FT_OUT + d8);
        const uint4 qn = *(const uint4*)(tab + (size_t)s_nstm[f] * FT_OUT + d8);
        accs[0] = __hfma2(*(const __half2*)&qs.x, v2, accs[0]);
        accs[1] = __hfma2(*(const __half2*)&qs.y, v2, accs[1]);
        accs[2] = __hfma2(*(const __half2*)&qs.z, v2, accs[2]);
        accs[3] = __hfma2(*(const __half2*)&qs.w, v2, accs[3]);
        accn[0] = __hfma2(*(const __half2*)&qn.x, v2, accn[0]);
        accn[1] = __hfma2(*(const __half2*)&qn.y, v2, accn[1]);
        accn[2] = __hfma2(*(const __half2*)&qn.z, v2, accn[2]);
        accn[3] = __hfma2(*(const __half2*)&qn.w, v2, accn[3]);
    }

    // bias + clip + dot with out_w; stm half at [d], nstm half at [FT_OUT + d]
    float partial = 0.f;
    #pragma unroll
    for (int j = 0; j < 4; ++j) {
        const float2 fs = __half22float2(accs[j]);
        const float2 fn = __half22float2(accn[j]);
        const int d = d8 + 2 * j;
        const float b0 = ft_b[d], b1 = ft_b[d + 1];
        const float hs0 = fminf(fmaxf(fs.x + b0, 0.f), 1.f);
        const float hs1 = fminf(fmaxf(fs.y + b1, 0.f), 1.f);
        const float hn0 = fminf(fmaxf(fn.x + b0, 0.f), 1.f);
        const float hn1 = fminf(fmaxf(fn.y + b1, 0.f), 1.f);
        partial = fmaf(hs0, out_w[d], partial);
        partial = fmaf(hs1, out_w[d + 1], partial);
        partial = fmaf(hn0, out_w[FT_OUT + d], partial);
        partial = fmaf(hn1, out_w[FT_OUT + d + 1], partial);
    }

    // wave (64-lane) shuffle reduce, then combine 2 waves
    #pragma unroll
    for (int off = 32; off > 0; off >>= 1)
        partial += __shfl_down(partial, off, 64);

    if ((t & 63) == 0) s_red[t >> 6] = partial;
    __syncthreads();

    if (t == 0) {
        const float total = s_red[0] + s_red[1] + out_b[0];
        out[b] = 1.f / (1.f + expf(-total));
    }
}

extern "C" void kernel_launch(void* const* d_in, const int* in_sizes, int n_in,
                              void* d_out, int out_size, void* d_ws, size_t ws_size,
                              hipStream_t stream) {
    const float* values   = (const float*)d_in[0];
    const int*   stm_idx  = (const int*)d_in[1];
    const int*   nstm_idx = (const int*)d_in[2];
    const float* ft_w     = (const float*)d_in[3];
    const float* ft_b     = (const float*)d_in[4];
    const float* out_w    = (const float*)d_in[5];
    const float* out_b    = (const float*)d_in[6];
    float*       out      = (float*)d_out;

    __half* tab = (__half*)d_ws;  // 768*1024*2 = 1.5 MB f16 table

    convert_kernel<<<(NFEAT * FT_OUT) / (256 * 4), 256, 0, stream>>>(
        ft_w, (__half2*)tab);
    nnboard_main<<<BATCH, 128, 0, stream>>>(
        values, stm_idx, nstm_idx, tab, ft_b, out_w, out_b, out);
}

// Round 4
// 112.526 us; speedup vs baseline: 1.8322x; 1.2882x over previous
//
#include <hip/hip_runtime.h>
#include <hip/hip_fp16.h>
#include <math.h>

#define BATCH 16384
#define MAXF 32
#define NFEAT 768
#define FT_OUT 1024
#define CHUNK 32                      // columns per chunk
#define NCHUNK (FT_OUT / CHUNK)       // 32 chunks
#define GROUPS 24                     // sample-group blocks per chunk (768 blocks = 3/CU)
#define CH_ELEMS (NFEAT * CHUNK)      // 24576 halves = 48 KiB per chunk

// compile-time component select for unrolled loops (f is a constant after unroll)
#define GET4(a, f) (((f) & 3) == 0 ? (a)[(f) >> 2].x : \
                    ((f) & 3) == 1 ? (a)[(f) >> 2].y : \
                    ((f) & 3) == 2 ? (a)[(f) >> 2].z : (a)[(f) >> 2].w)

// Phase 0: fp32 table -> f16, chunk-major layout: tab[chunk][row][CHUNK]
__global__ __launch_bounds__(256) void convert_kernel(const float* __restrict__ ft_w,
                                                      __half* __restrict__ tab) {
    const int i = (blockIdx.x * 256 + threadIdx.x) * 4;   // flat elem index
    const int r = i >> 10;            // row (i / 1024)
    const int col = i & 1023;
    const int c = col >> 5;           // chunk
    const int within = col & 31;      // all 4 elems in same chunk (4 | 32)
    float4 f = *(const float4*)(ft_w + i);
    __half2 lo = __floats2half2_rn(f.x, f.y);
    __half2 hi = __floats2half2_rn(f.z, f.w);
    __half2* dst = (__half2*)(tab + (size_t)c * CH_ELEMS + r * CHUNK + within);
    dst[0] = lo;
    dst[1] = hi;
}

// Phase 1: block = (chunk c, group g). Stage chunk to LDS, stream samples against it.
// 4 lanes per sample; lane j owns cols [32c+8j, 32c+8j+8). Partial logit -> atomicAdd.
__global__ __launch_bounds__(256, 3) void nnboard_main(
    const float* __restrict__ values,
    const int*   __restrict__ stm_idx,
    const int*   __restrict__ nstm_idx,
    const __half* __restrict__ tab,
    const float* __restrict__ ft_b,
    const float* __restrict__ out_w,
    float*       __restrict__ logits)
{
    __shared__ __half s_tab[CH_ELEMS];    // 48 KiB

    const int tid = threadIdx.x;
    const int c = blockIdx.x % NCHUNK;
    const int g = blockIdx.x / NCHUNK;    // 0..GROUPS-1

    // stage chunk: 3072 uint4s, perfectly coalesced (chunk-major ws layout)
    {
        const uint4* src = (const uint4*)(tab + (size_t)c * CH_ELEMS);
        uint4* dst = (uint4*)s_tab;
        #pragma unroll
        for (int k = 0; k < CH_ELEMS / 8 / 256; ++k)
            dst[k * 256 + tid] = src[k * 256 + tid];
    }
    __syncthreads();

    const int grp = tid >> 2;             // 0..63 : sample slot within s_iter
    const int j   = tid & 3;              // lane within sample group
    const int col0 = c * CHUNK + j * 8;   // global col base for this lane
    const __half* my_tab = s_tab + j * 8; // + row*CHUNK per gathered row

    // lane-constant epilogue coefficients (4 distinct addrs per wave -> cheap)
    const float4 bia0 = *(const float4*)(ft_b + col0);
    const float4 bia1 = *(const float4*)(ft_b + col0 + 4);
    const float4 ws0  = *(const float4*)(out_w + col0);
    const float4 ws1  = *(const float4*)(out_w + col0 + 4);
    const float4 wn0  = *(const float4*)(out_w + FT_OUT + col0);
    const float4 wn1  = *(const float4*)(out_w + FT_OUT + col0 + 4);

    const __half2 zero2 = __float2half2_rn(0.f);

    for (int it = g; it < BATCH / 64; it += GROUPS) {
        const int b = it * 64 + grp;

        // vectorized register preload of this sample's indices + values
        const int4*   sp = (const int4*)(stm_idx + b * MAXF);
        const int4*   np = (const int4*)(nstm_idx + b * MAXF);
        const float4* vp = (const float4*)(values + b * MAXF);
        int4 si[8], ni[8];
        float4 vv[8];
        #pragma unroll
        for (int k = 0; k < 8; ++k) { si[k] = sp[k]; ni[k] = np[k]; vv[k] = vp[k]; }

        __half2 accs[4] = {zero2, zero2, zero2, zero2};
        __half2 accn[4] = {zero2, zero2, zero2, zero2};

        #pragma unroll
        for (int f = 0; f < MAXF; ++f) {
            const int is = GET4(si, f);
            const int in = GET4(ni, f);
            const __half2 v2 = __float2half2_rn(GET4(vv, f));
            const uint4 qs = *(const uint4*)(my_tab + is * CHUNK);
            const uint4 qn = *(const uint4*)(my_tab + in * CHUNK);
            accs[0] = __hfma2(*(const __half2*)&qs.x, v2, accs[0]);
            accs[1] = __hfma2(*(const __half2*)&qs.y, v2, accs[1]);
            accs[2] = __hfma2(*(const __half2*)&qs.z, v2, accs[2]);
            accs[3] = __hfma2(*(const __half2*)&qs.w, v2, accs[3]);
            accn[0] = __hfma2(*(const __half2*)&qn.x, v2, accn[0]);
            accn[1] = __hfma2(*(const __half2*)&qn.y, v2, accn[1]);
            accn[2] = __hfma2(*(const __half2*)&qn.z, v2, accn[2]);
            accn[3] = __hfma2(*(const __half2*)&qn.w, v2, accn[3]);
        }

        // bias + clip + dot for this lane's 8 cols, both slices
        float p = 0.f;
        {
            const float2 f0 = __half22float2(accs[0]);
            const float2 f1 = __half22float2(accs[1]);
            const float2 f2 = __half22float2(accs[2]);
            const float2 f3 = __half22float2(accs[3]);
            const float2 g0 = __half22float2(accn[0]);
            const float2 g1 = __half22float2(accn[1]);
            const float2 g2 = __half22float2(accn[2]);
            const float2 g3 = __half22float2(accn[3]);
            auto clip = [](float x) { return fminf(fmaxf(x, 0.f), 1.f); };
            p = fmaf(clip(f0.x + bia0.x), ws0.x, p);
            p = fmaf(clip(f0.y + bia0.y), ws0.y, p);
            p = fmaf(clip(f1.x + bia0.z), ws0.z, p);
            p = fmaf(clip(f1.y + bia0.w), ws0.w, p);
            p = fmaf(clip(f2.x + bia1.x), ws1.x, p);
            p = fmaf(clip(f2.y + bia1.y), ws1.y, p);
            p = fmaf(clip(f3.x + bia1.z), ws1.z, p);
            p = fmaf(clip(f3.y + bia1.w), ws1.w, p);
            p = fmaf(clip(g0.x + bia0.x), wn0.x, p);
            p = fmaf(clip(g0.y + bia0.y), wn0.y, p);
            p = fmaf(clip(g1.x + bia0.z), wn0.z, p);
            p = fmaf(clip(g1.y + bia0.w), wn0.w, p);
            p = fmaf(clip(g2.x + bia1.x), wn1.x, p);
            p = fmaf(clip(g2.y + bia1.y), wn1.y, p);
            p = fmaf(clip(g3.x + bia1.z), wn1.z, p);
            p = fmaf(clip(g3.y + bia1.w), wn1.w, p);
        }

        // reduce 4 lanes of the group
        p += __shfl_down(p, 1, 64);
        p += __shfl_down(p, 2, 64);
        if (j == 0) atomicAdd(logits + b, p);
    }
}

// Phase 2: sigmoid(logit + out_b)
__global__ __launch_bounds__(256) void sigmoid_kernel(const float* __restrict__ logits,
                                                      const float* __restrict__ out_b,
                                                      float* __restrict__ out) {
    const int i = blockIdx.x * 256 + threadIdx.x;
    out[i] = 1.f / (1.f + expf(-(logits[i] + out_b[0])));
}

extern "C" void kernel_launch(void* const* d_in, const int* in_sizes, int n_in,
                              void* d_out, int out_size, void* d_ws, size_t ws_size,
                              hipStream_t stream) {
    const float* values   = (const float*)d_in[0];
    const int*   stm_idx  = (const int*)d_in[1];
    const int*   nstm_idx = (const int*)d_in[2];
    const float* ft_w     = (const float*)d_in[3];
    const float* ft_b     = (const float*)d_in[4];
    const float* out_w    = (const float*)d_in[5];
    const float* out_b    = (const float*)d_in[6];
    float*       out      = (float*)d_out;

    __half* tab    = (__half*)d_ws;                               // 1.5 MB, chunk-major
    float*  logits = (float*)((char*)d_ws + (size_t)NCHUNK * CH_ELEMS * 2); // 64 KB

    convert_kernel<<<(NFEAT * FT_OUT) / (256 * 4), 256, 0, stream>>>(ft_w, tab);
    hipMemsetAsync(logits, 0, BATCH * sizeof(float), stream);
    nnboard_main<<<NCHUNK * GROUPS, 256, 0, stream>>>(
        values, stm_idx, nstm_idx, tab, ft_b, out_w, logits);
    sigmoid_kernel<<<BATCH / 256, 256, 0, stream>>>(logits, out_b, out);
}